// Round 2
// baseline (213.718 us; speedup 1.0000x reference)
//
#include <hip/hip_runtime.h>

// CenterLoss: loss = (1/B) * sum_i ||f_i - c_{l_i}||^2 / (counts_{l_i} * D)
// B=65536, D=512, C=1000, fp32 in / fp32 scalar out.
// Memory-bound: 128 MiB feature read -> ~21 us floor at 6.3 TB/s.
//
// Structure: (1) int histogram of labels; (2) per-sample scaled distance,
// 4 samples per wave, one wave+block reduction, block partial to ws (no fp32
// atomics); (3) reduce 4096 partials.

#define WAVE 64
constexpr int WAVES_PER_BLOCK  = 4;
constexpr int SAMPLES_PER_WAVE = 4;
constexpr int SAMPLES_PER_BLOCK = WAVES_PER_BLOCK * SAMPLES_PER_WAVE; // 16

__global__ __launch_bounds__(256) void count_kernel(
    const int* __restrict__ labels, int* __restrict__ counts, int batch)
{
    int i = blockIdx.x * blockDim.x + threadIdx.x;
    if (i < batch) atomicAdd(&counts[labels[i]], 1);
}

__global__ __launch_bounds__(256) void dist_kernel(
    const float* __restrict__ features,   // [batch, feat]
    const float* __restrict__ centers,    // [nclass, feat]
    const int*   __restrict__ labels,     // [batch]
    const int*   __restrict__ counts,     // [nclass]
    float* __restrict__ partials,         // [gridDim.x]
    int batch, int feat)
{
    const int wid  = threadIdx.x >> 6;
    const int lane = threadIdx.x & 63;
    const int base = blockIdx.x * SAMPLES_PER_BLOCK + wid * SAMPLES_PER_WAVE;
    const int n4   = feat >> 2;                       // 128 float4 per row

    float local = 0.0f;
#pragma unroll
    for (int s = 0; s < SAMPLES_PER_WAVE; ++s) {
        const int sample = base + s;
        if (sample >= batch) break;                   // wave-uniform
        const int label = labels[sample];

        const float4* __restrict__ f4 =
            (const float4*)(features + (size_t)sample * feat);
        const float4* __restrict__ c4 =
            (const float4*)(centers + (size_t)label * feat);

        float acc = 0.0f;
#pragma unroll 2
        for (int idx = lane; idx < n4; idx += WAVE) {
            float4 fv = f4[idx];
            float4 cv = c4[idx];
            float dx = fv.x - cv.x;
            float dy = fv.y - cv.y;
            float dz = fv.z - cv.z;
            float dw = fv.w - cv.w;
            acc += dx * dx + dy * dy + dz * dz + dw * dw;
        }
        // counts[label] >= 1 whenever label appears -> no div-by-zero
        local += acc / ((float)counts[label] * (float)feat);
    }

    // one wave-64 butterfly reduce per wave (not per sample)
#pragma unroll
    for (int off = 32; off > 0; off >>= 1)
        local += __shfl_down(local, off, WAVE);

    __shared__ float wpart[WAVES_PER_BLOCK];
    if (lane == 0) wpart[wid] = local;
    __syncthreads();
    if (threadIdx.x == 0)
        partials[blockIdx.x] = wpart[0] + wpart[1] + wpart[2] + wpart[3];
}

__global__ __launch_bounds__(256) void reduce_kernel(
    const float* __restrict__ partials, int n,
    float* __restrict__ out, int batch)
{
    float acc = 0.0f;
    for (int i = threadIdx.x; i < n; i += 256) acc += partials[i];

#pragma unroll
    for (int off = 32; off > 0; off >>= 1)
        acc += __shfl_down(acc, off, WAVE);

    __shared__ float wpart[4];
    const int lane = threadIdx.x & 63;
    const int wid  = threadIdx.x >> 6;
    if (lane == 0) wpart[wid] = acc;
    __syncthreads();
    if (threadIdx.x == 0)
        out[0] = (wpart[0] + wpart[1] + wpart[2] + wpart[3]) / (float)batch;
}

extern "C" void kernel_launch(void* const* d_in, const int* in_sizes, int n_in,
                              void* d_out, int out_size, void* d_ws, size_t ws_size,
                              hipStream_t stream) {
    const float* features = (const float*)d_in[0];
    const float* centers  = (const float*)d_in[1];
    const int*   labels   = (const int*)d_in[2];

    const int batch  = in_sizes[2];                 // 65536
    const int feat   = in_sizes[0] / batch;         // 512
    const int nclass = in_sizes[1] / feat;          // 1000

    int*   counts   = (int*)d_ws;
    float* partials = (float*)((char*)d_ws + ((nclass * sizeof(int) + 255) & ~255));

    // zero the count accumulators (ws is poisoned to 0xAA before every call)
    hipMemsetAsync(counts, 0, (size_t)nclass * sizeof(int), stream);

    count_kernel<<<(batch + 255) / 256, 256, 0, stream>>>(labels, counts, batch);

    const int nblocks = (batch + SAMPLES_PER_BLOCK - 1) / SAMPLES_PER_BLOCK; // 4096
    dist_kernel<<<nblocks, 256, 0, stream>>>(
        features, centers, labels, counts, partials, batch, feat);

    reduce_kernel<<<1, 256, 0, stream>>>(partials, nblocks, (float*)d_out, batch);
}